// Round 8
// baseline (867.925 us; speedup 1.0000x reference)
//
#include <hip/hip_runtime.h>

#define BSHIFT 7
#define BWIDTH 128
#define PBLK   256        // chunks for hist/place (also their grid size)
#define PTHR   1024

typedef int v4i __attribute__((ext_vector_type(4)));
typedef float v2f __attribute__((ext_vector_type(2)));

// ---------------- fp8 e4m3 helpers (HW cvt with manual fallback) ----------------

#if __has_builtin(__builtin_amdgcn_cvt_pk_f32_fp8) && __has_builtin(__builtin_amdgcn_cvt_pk_fp8_f32)
#define FP8_HW 1
#else
#define FP8_HW 0
#endif

__device__ __forceinline__ unsigned enc1_sw(float f) {
    unsigned u = __float_as_uint(f), s = u >> 31;
    float m = fabsf(f);
    unsigned code;
    if (!(m == m)) code = 0x7F;
    else if (m >= 448.f) code = 0x7E;
    else if (m < 0.015625f) {
        code = (unsigned)(int)rintf(m * 512.f);
    } else {
        int e = (int)((__float_as_uint(m) >> 23) & 255) - 127;
        if (e > 8) e = 8;
        float sc = __uint_as_float((unsigned)(130 - e) << 23);
        int qi = (int)rintf(m * sc);
        if (qi >= 16) { e++; qi = 8; }
        code = (e > 8) ? 0x7E : (((unsigned)(e + 7) << 3) | (unsigned)(qi - 8));
    }
    return code | (s << 7);
}

__device__ __forceinline__ float dec1_sw(unsigned b) {
    unsigned s = b >> 7, e = (b >> 3) & 15, m = b & 7;
    float v;
    if (e == 0) v = (float)m * 0.001953125f;
    else        v = (float)(8 + m) * __uint_as_float((e + 117) << 23);
    return s ? -v : v;
}

__device__ __forceinline__ unsigned enc4(float f0, float f1, float f2, float f3) {
#if FP8_HW
    int w = __builtin_amdgcn_cvt_pk_fp8_f32(f0, f1, 0, false);
    w = __builtin_amdgcn_cvt_pk_fp8_f32(f2, f3, w, true);
    return (unsigned)w;
#else
    return enc1_sw(f0) | (enc1_sw(f1) << 8) | (enc1_sw(f2) << 16) | (enc1_sw(f3) << 24);
#endif
}

__device__ __forceinline__ void dec4(unsigned w, float* o) {
#if FP8_HW
    v2f lo = __builtin_amdgcn_cvt_pk_f32_fp8((int)w, false);
    v2f hi = __builtin_amdgcn_cvt_pk_f32_fp8((int)w, true);
    o[0] = lo[0]; o[1] = lo[1]; o[2] = hi[0]; o[3] = hi[1];
#else
    o[0] = dec1_sw(w & 255); o[1] = dec1_sw((w >> 8) & 255);
    o[2] = dec1_sw((w >> 16) & 255); o[3] = dec1_sw(w >> 24);
#endif
}

// ---------------- bucket-grouped edge staging (global-atomic-free) ----------------

__global__ __launch_bounds__(PTHR) void k_histb(const v4i* __restrict__ col4,
        int E4, int nbuck, int* __restrict__ hh) {
    __shared__ int h[1024];
    int t = threadIdx.x;
    for (int i = t; i < nbuck; i += PTHR) h[i] = 0;
    __syncthreads();
    int per = (E4 + PBLK - 1) / PBLK;
    int beg = blockIdx.x * per;
    int end = min(beg + per, E4);
    for (int i = beg + t; i < end; i += PTHR) {
        v4i c = __builtin_nontemporal_load(&col4[i]);
        atomicAdd(&h[c[0] >> BSHIFT], 1);
        atomicAdd(&h[c[1] >> BSHIFT], 1);
        atomicAdd(&h[c[2] >> BSHIFT], 1);
        atomicAdd(&h[c[3] >> BSHIFT], 1);
    }
    __syncthreads();
    for (int b = t; b < nbuck; b += PTHR)
        hh[b * PBLK + blockIdx.x] = h[b];
}

__global__ __launch_bounds__(1024) void k_scanA(int* __restrict__ hh, int total,
                                                int* __restrict__ part) {
    __shared__ int s[1024];
    int t = threadIdx.x;
    int i = blockIdx.x * 1024 + t;
    int v = (i < total) ? hh[i] : 0;
    s[t] = v;
    __syncthreads();
    for (int off = 1; off < 1024; off <<= 1) {
        int u = (t >= off) ? s[t - off] : 0;
        __syncthreads();
        s[t] += u;
        __syncthreads();
    }
    if (i < total) hh[i] = s[t] - v;
    if (t == 1023) part[blockIdx.x] = s[t];
}

__global__ __launch_bounds__(1024) void k_scanB(int* __restrict__ part, int nch,
                                                float* __restrict__ gsum) {
    __shared__ int s[1024];
    int t = threadIdx.x;
    int v = (t < nch) ? part[t] : 0;
    s[t] = v;
    __syncthreads();
    for (int off = 1; off < 1024; off <<= 1) {
        int u = (t >= off) ? s[t - off] : 0;
        __syncthreads();
        s[t] += u;
        __syncthreads();
    }
    if (t < nch) part[t] = s[t] - v;
    if (t < 32) gsum[t] = 0.f;
}

__global__ __launch_bounds__(1024) void k_scanC(int* __restrict__ hh, int total,
                                                const int* __restrict__ part) {
    int i = blockIdx.x * 1024 + threadIdx.x;
    if (i < total) hh[i] += part[blockIdx.x];
}

__global__ __launch_bounds__(PTHR) void k_place(const v4i* __restrict__ row4,
        const v4i* __restrict__ col4, const int* __restrict__ hh,
        unsigned* __restrict__ staging, int E4, int nbuck) {
    __shared__ int sbase[1024];
    __shared__ int lfill[1024];
    int t = threadIdx.x;
    for (int b = t; b < nbuck; b += PTHR) {
        sbase[b] = hh[b * PBLK + blockIdx.x];
        lfill[b] = 0;
    }
    __syncthreads();
    int per = (E4 + PBLK - 1) / PBLK;
    int beg = blockIdx.x * per;
    int end = min(beg + per, E4);
    for (int i = beg + t; i < end; i += PTHR) {
        v4i c = __builtin_nontemporal_load(&col4[i]);
        v4i r = __builtin_nontemporal_load(&row4[i]);
#pragma unroll
        for (int q = 0; q < 4; q++) {
            int b = c[q] >> BSHIFT;
            int pos = sbase[b] + atomicAdd(&lfill[b], 1);
            staging[pos] = (unsigned)r[q] | ((unsigned)(c[q] & (BWIDTH - 1)) << 17);
        }
    }
}

// per-bucket degree -> dis (no ptr/csr needed anymore)
__global__ __launch_bounds__(256) void k_deg(const unsigned* __restrict__ staging,
        const int* __restrict__ hh, float* __restrict__ dis, int N, int E, int nbuck) {
    __shared__ int hist[BWIDTH];
    int b = blockIdx.x;
    int base = hh[b * PBLK];
    int nxt  = (b + 1 < nbuck) ? hh[(b + 1) * PBLK] : E;
    int cnt = nxt - base;
    int t = threadIdx.x;
    if (t < BWIDTH) hist[t] = 0;
    __syncthreads();
    for (int i = t; i < cnt; i += 256)
        atomicAdd(&hist[staging[base + i] >> 17], 1);
    __syncthreads();
    if (t < BWIDTH) {
        int node = (b << BSHIFT) + t;
        if (node < N) dis[node] = rsqrtf((float)(hist[t] + 1));   // +1 self-loop
    }
}

// ---------------- GNN compute ----------------

__global__ void k_zs1(const float4* __restrict__ x, const float* __restrict__ dis,
                      float4* __restrict__ zs1, int n) {
    int i = blockIdx.x * blockDim.x + threadIdx.x;
    if (i < n) {
        float d = dis[i];
        float4 v = x[i];
        v.x *= d; v.y *= d; v.z *= d; v.w *= d;
        zs1[i] = v;
    }
}

// edge-parallel per-bucket: LDS float4 accumulate + fused MLP -> fp8 zs2
__global__ __launch_bounds__(1024) void k_prop1b(const unsigned* __restrict__ staging,
        const int* __restrict__ hh, const float4* __restrict__ zs1,
        const float* __restrict__ dis, const float* __restrict__ W1,
        const float* __restrict__ b1, const float* __restrict__ W2,
        unsigned* __restrict__ zs2f8, int N, int E, int nbuck) {
    __shared__ float lacc[BWIDTH * 4];
    __shared__ float sW1[256], sb1[64], sW2[2048];
    int t = threadIdx.x;
    if (t < 256) sW1[t] = W1[t];
    if (t < 64)  sb1[t] = b1[t];
    for (int i = t; i < 2048; i += 1024) sW2[i] = W2[i];
    if (t < BWIDTH * 4) lacc[t] = 0.f;
    __syncthreads();
    int b = blockIdx.x;
    int base = hh[b * PBLK];
    int nxt  = (b + 1 < nbuck) ? hh[(b + 1) * PBLK] : E;
    int cnt = nxt - base;
    for (int i = t; i < cnt; i += 1024) {
        unsigned p = staging[base + i];
        int r = (int)(p & 0x1FFFFu);
        int c = (int)(p >> 17);
        float4 u = zs1[r];
        int cb = c * 4;
        // rotate low 2 bits by c: spreads the 8-way bank aliasing to ~2-way
        atomicAdd(&lacc[cb + ((0 + c) & 3)], u.x);
        atomicAdd(&lacc[cb + ((1 + c) & 3)], u.y);
        atomicAdd(&lacc[cb + ((2 + c) & 3)], u.z);
        atomicAdd(&lacc[cb + ((3 + c) & 3)], u.w);
    }
    __syncthreads();
    int c = t >> 3, jj = t & 7;
    int node = (b << BSHIFT) + c;
    if (node >= N) return;
    float d = dis[node];
    float4 self = zs1[node];
    int cb = c * 4;
    float p0 = (lacc[cb + ((0 + c) & 3)] + self.x) * d;
    float p1 = (lacc[cb + ((1 + c) & 3)] + self.y) * d;
    float p2 = (lacc[cb + ((2 + c) & 3)] + self.z) * d;
    float p3 = (lacc[cb + ((3 + c) & 3)] + self.w) * d;
    float a0 = 0.f, a1 = 0.f, a2 = 0.f, a3 = 0.f;
    int col = jj * 4;
    for (int k = 0; k < 64; k++) {
        float tv = fmaxf(p0 * sW1[k] + p1 * sW1[64 + k] + p2 * sW1[128 + k]
                         + p3 * sW1[192 + k] + sb1[k], 0.f);
        const float* w2 = &sW2[k * 32 + col];
        a0 += tv * w2[0]; a1 += tv * w2[1]; a2 += tv * w2[2]; a3 += tv * w2[3];
    }
    zs2f8[(size_t)node * 8 + jj] = enc4(a0 * d, a1 * d, a2 * d, a3 * d);
}

// edge-parallel per-bucket: LDS 128x32 f32 accumulate (bank-rotated), fp8 gathers,
// finalize relu(+b2) + mean-pool partials
__global__ __launch_bounds__(1024) void k_prop2b(const unsigned* __restrict__ zs2f8,
        const unsigned* __restrict__ staging, const int* __restrict__ hh,
        const float* __restrict__ dis, const float* __restrict__ b2,
        float* __restrict__ gsum, int N, int E, int nbuck) {
    __shared__ float lacc[BWIDTH * 32];   // 16 KB
    __shared__ float gacc[32];
    int t = threadIdx.x;
    for (int i = t; i < BWIDTH * 32; i += 1024) lacc[i] = 0.f;
    if (t < 32) gacc[t] = 0.f;
    __syncthreads();
    int b = blockIdx.x;
    int base = hh[b * PBLK];
    int nxt  = (b + 1 < nbuck) ? hh[(b + 1) * PBLK] : E;
    int cnt = nxt - base;
    int j = t & 7;
    int f = j * 4;
    for (int i = (t >> 3); i < cnt; i += 128) {
        unsigned p = staging[base + i];
        int r = (int)(p & 0x1FFFFu);
        int c = (int)(p >> 17);
        float u[4];
        dec4(zs2f8[(size_t)r * 8 + j], u);      // one 32B line per edge (8 lanes)
        int cb = c * 32, rot = c * 4;
        atomicAdd(&lacc[cb + ((f + 0 + rot) & 31)], u[0]);
        atomicAdd(&lacc[cb + ((f + 1 + rot) & 31)], u[1]);
        atomicAdd(&lacc[cb + ((f + 2 + rot) & 31)], u[2]);
        atomicAdd(&lacc[cb + ((f + 3 + rot) & 31)], u[3]);
    }
    __syncthreads();
    int c = t >> 3;
    int node = (b << BSHIFT) + c;
    if (node < N) {
        float d = dis[node];
        float self[4];
        dec4(zs2f8[(size_t)node * 8 + j], self);
        int cb = c * 32, rot = c * 4;
#pragma unroll
        for (int m = 0; m < 4; m++) {
            float a = lacc[cb + ((f + m + rot) & 31)] + self[m];
            a = fmaxf(a * d + b2[f + m], 0.f);
            atomicAdd(&gacc[f + m], a);
        }
    }
    __syncthreads();
    if (t < 32) atomicAdd(&gsum[t], gacc[t]);
}

__global__ void k_final(const float* __restrict__ gsum, const float* __restrict__ Wfc,
                        const float* __restrict__ bfc, float* __restrict__ out, int n) {
    __shared__ float s[32];
    int t = threadIdx.x;
    if (t < 32) s[t] = (gsum[t] / (float)n) * Wfc[t];
    __syncthreads();
    if (t == 0) {
        float a = 0.f;
        for (int i = 0; i < 32; i++) a += s[i];
        a += bfc[0];
        out[0] = 1.f / (1.f + expf(-a));
    }
}

// ---------------- launch ----------------

extern "C" void kernel_launch(void* const* d_in, const int* in_sizes, int n_in,
                              void* d_out, int out_size, void* d_ws, size_t ws_size,
                              hipStream_t stream) {
    const float* x    = (const float*)d_in[0];
    const int*   ei   = (const int*)d_in[1];     // int32 per harness contract
    const float* W1   = (const float*)d_in[2];
    const float* b1   = (const float*)d_in[3];
    const float* W2   = (const float*)d_in[4];
    const float* b2   = (const float*)d_in[5];
    const float* Wfc  = (const float*)d_in[6];
    const float* bfc  = (const float*)d_in[7];
    float* out = (float*)d_out;

    const int N = in_sizes[0] / 4;
    const int E = in_sizes[1] / 2;
    const int E4 = E / 4;
    const int nbuck = (N + BWIDTH - 1) >> BSHIFT;      // 782
    const int total = nbuck * PBLK;                    // 200192
    const int nch   = (total + 1023) / 1024;           // 196 (<=1024)

    auto align = [](size_t v) { return (v + 255) & ~(size_t)255; };
    char* w = (char*)d_ws;
    int*      hh      = (int*)w;      w += align((size_t)total * 4);
    int*      part    = (int*)w;      w += align(1024 * 4);
    unsigned* staging = (unsigned*)w; w += align((size_t)E * 4);
    float*    dis     = (float*)w;    w += align((size_t)N * 4);
    float*    zs1     = (float*)w;    w += align((size_t)N * 16);
    unsigned* zs2f8   = (unsigned*)w; w += align((size_t)N * 32);
    float*    gsum    = (float*)w;    w += align(32 * 4);

    const int nb = (N + 255) / 256;

    k_histb<<<PBLK, PTHR, 0, stream>>>((const v4i*)(ei + E), E4, nbuck, hh);
    k_scanA<<<nch, 1024, 0, stream>>>(hh, total, part);
    k_scanB<<<1, 1024, 0, stream>>>(part, nch, gsum);
    k_scanC<<<nch, 1024, 0, stream>>>(hh, total, part);
    k_place<<<PBLK, PTHR, 0, stream>>>((const v4i*)ei, (const v4i*)(ei + E),
                                       hh, staging, E4, nbuck);
    k_deg<<<nbuck, 256, 0, stream>>>(staging, hh, dis, N, E, nbuck);
    k_zs1<<<nb, 256, 0, stream>>>((const float4*)x, dis, (float4*)zs1, N);
    k_prop1b<<<nbuck, 1024, 0, stream>>>(staging, hh, (const float4*)zs1, dis,
                                         W1, b1, W2, zs2f8, N, E, nbuck);
    k_prop2b<<<nbuck, 1024, 0, stream>>>(zs2f8, staging, hh, dis, b2, gsum, N, E, nbuck);
    k_final<<<1, 64, 0, stream>>>(gsum, Wfc, bfc, out, N);
}

// Round 9
// 189.336 us; speedup vs baseline: 4.5840x; 4.5840x over previous
//
#include <hip/hip_runtime.h>

#define BSHIFT 7
#define BWIDTH 128
#define PBLK   256        // chunks for hist/place (also their grid size)
#define PTHR   1024
#define ECAP   6144       // LDS edge cache in k_build (24KB); avg bucket ~4100

typedef int v4i __attribute__((ext_vector_type(4)));
typedef float v2f __attribute__((ext_vector_type(2)));

// ---------------- fp8 e4m3 helpers (HW cvt with manual fallback) ----------------

#if __has_builtin(__builtin_amdgcn_cvt_pk_f32_fp8) && __has_builtin(__builtin_amdgcn_cvt_pk_fp8_f32)
#define FP8_HW 1
#else
#define FP8_HW 0
#endif

__device__ __forceinline__ unsigned enc1_sw(float f) {
    unsigned u = __float_as_uint(f), s = u >> 31;
    float m = fabsf(f);
    unsigned code;
    if (!(m == m)) code = 0x7F;
    else if (m >= 448.f) code = 0x7E;
    else if (m < 0.015625f) {
        code = (unsigned)(int)rintf(m * 512.f);
    } else {
        int e = (int)((__float_as_uint(m) >> 23) & 255) - 127;
        if (e > 8) e = 8;
        float sc = __uint_as_float((unsigned)(130 - e) << 23);
        int qi = (int)rintf(m * sc);
        if (qi >= 16) { e++; qi = 8; }
        code = (e > 8) ? 0x7E : (((unsigned)(e + 7) << 3) | (unsigned)(qi - 8));
    }
    return code | (s << 7);
}

__device__ __forceinline__ float dec1_sw(unsigned b) {
    unsigned s = b >> 7, e = (b >> 3) & 15, m = b & 7;
    float v;
    if (e == 0) v = (float)m * 0.001953125f;
    else        v = (float)(8 + m) * __uint_as_float((e + 117) << 23);
    return s ? -v : v;
}

__device__ __forceinline__ unsigned enc4(float f0, float f1, float f2, float f3) {
#if FP8_HW
    int w = __builtin_amdgcn_cvt_pk_fp8_f32(f0, f1, 0, false);
    w = __builtin_amdgcn_cvt_pk_fp8_f32(f2, f3, w, true);
    return (unsigned)w;
#else
    return enc1_sw(f0) | (enc1_sw(f1) << 8) | (enc1_sw(f2) << 16) | (enc1_sw(f3) << 24);
#endif
}

__device__ __forceinline__ void dec4(unsigned w, float* o) {
#if FP8_HW
    v2f lo = __builtin_amdgcn_cvt_pk_f32_fp8((int)w, false);
    v2f hi = __builtin_amdgcn_cvt_pk_f32_fp8((int)w, true);
    o[0] = lo[0]; o[1] = lo[1]; o[2] = hi[0]; o[3] = hi[1];
#else
    o[0] = dec1_sw(w & 255); o[1] = dec1_sw((w >> 8) & 255);
    o[2] = dec1_sw((w >> 16) & 255); o[3] = dec1_sw(w >> 24);
#endif
}

// ---------------- bucket-grouped edge staging (global-atomic-free) ----------------

__global__ __launch_bounds__(PTHR) void k_histb(const v4i* __restrict__ col4,
        int E4, int nbuck, int* __restrict__ hh) {
    __shared__ int h[1024];
    int t = threadIdx.x;
    for (int i = t; i < nbuck; i += PTHR) h[i] = 0;
    __syncthreads();
    int per = (E4 + PBLK - 1) / PBLK;
    int beg = blockIdx.x * per;
    int end = min(beg + per, E4);
    for (int i = beg + t; i < end; i += PTHR) {
        v4i c = __builtin_nontemporal_load(&col4[i]);
        atomicAdd(&h[c[0] >> BSHIFT], 1);
        atomicAdd(&h[c[1] >> BSHIFT], 1);
        atomicAdd(&h[c[2] >> BSHIFT], 1);
        atomicAdd(&h[c[3] >> BSHIFT], 1);
    }
    __syncthreads();
    for (int b = t; b < nbuck; b += PTHR)
        hh[b * PBLK + blockIdx.x] = h[b];
}

__global__ __launch_bounds__(1024) void k_scanA(int* __restrict__ hh, int total,
                                                int* __restrict__ part) {
    __shared__ int s[1024];
    int t = threadIdx.x;
    int i = blockIdx.x * 1024 + t;
    int v = (i < total) ? hh[i] : 0;
    s[t] = v;
    __syncthreads();
    for (int off = 1; off < 1024; off <<= 1) {
        int u = (t >= off) ? s[t - off] : 0;
        __syncthreads();
        s[t] += u;
        __syncthreads();
    }
    if (i < total) hh[i] = s[t] - v;
    if (t == 1023) part[blockIdx.x] = s[t];
}

__global__ __launch_bounds__(1024) void k_scanB(int* __restrict__ part, int nch,
        float* __restrict__ gsum, int* __restrict__ ptr, int N, int E) {
    __shared__ int s[1024];
    int t = threadIdx.x;
    int v = (t < nch) ? part[t] : 0;
    s[t] = v;
    __syncthreads();
    for (int off = 1; off < 1024; off <<= 1) {
        int u = (t >= off) ? s[t - off] : 0;
        __syncthreads();
        s[t] += u;
        __syncthreads();
    }
    if (t < nch) part[t] = s[t] - v;
    if (t < 32) gsum[t] = 0.f;
    if (t == 0) ptr[N] = E;
}

__global__ __launch_bounds__(1024) void k_scanC(int* __restrict__ hh, int total,
                                                const int* __restrict__ part) {
    int i = blockIdx.x * 1024 + threadIdx.x;
    if (i < total) hh[i] += part[blockIdx.x];
}

__global__ __launch_bounds__(PTHR) void k_place(const v4i* __restrict__ row4,
        const v4i* __restrict__ col4, const int* __restrict__ hh,
        unsigned* __restrict__ staging, int E4, int nbuck) {
    __shared__ int sbase[1024];
    __shared__ int lfill[1024];
    int t = threadIdx.x;
    for (int b = t; b < nbuck; b += PTHR) {
        sbase[b] = hh[b * PBLK + blockIdx.x];
        lfill[b] = 0;
    }
    __syncthreads();
    int per = (E4 + PBLK - 1) / PBLK;
    int beg = blockIdx.x * per;
    int end = min(beg + per, E4);
    for (int i = beg + t; i < end; i += PTHR) {
        v4i c = __builtin_nontemporal_load(&col4[i]);
        v4i r = __builtin_nontemporal_load(&row4[i]);
#pragma unroll
        for (int q = 0; q < 4; q++) {
            int b = c[q] >> BSHIFT;
            int pos = sbase[b] + atomicAdd(&lfill[b], 1);
            staging[pos] = (unsigned)r[q] | ((unsigned)(c[q] & (BWIDTH - 1)) << 17);
        }
    }
}

// per-bucket: node degrees -> ptr/dis/zs1, CSR slices; bucket edges cached in LDS
__global__ __launch_bounds__(256) void k_build(const unsigned* __restrict__ staging,
        const int* __restrict__ hh, int* __restrict__ ptr, float* __restrict__ dis,
        int* __restrict__ csr, const float4* __restrict__ x, float4* __restrict__ zs1,
        int N, int E, int nbuck) {
    __shared__ unsigned ecache[ECAP];
    __shared__ int hist[BWIDTH], scn[BWIDTH], fl[BWIDTH];
    int b = blockIdx.x;
    int base = hh[b * PBLK];
    int nxt  = (b + 1 < nbuck) ? hh[(b + 1) * PBLK] : E;
    int cnt = nxt - base;
    int t = threadIdx.x;
    bool useC = (cnt <= ECAP);
    if (t < BWIDTH) { hist[t] = 0; fl[t] = 0; }
    __syncthreads();
    if (useC) {
        for (int i = t; i < cnt; i += 256) {
            unsigned p = staging[base + i];
            ecache[i] = p;
            atomicAdd(&hist[p >> 17], 1);
        }
    } else {
        for (int i = t; i < cnt; i += 256)
            atomicAdd(&hist[staging[base + i] >> 17], 1);
    }
    __syncthreads();
    if (t < BWIDTH) scn[t] = hist[t];
    __syncthreads();
    for (int off = 1; off < BWIDTH; off <<= 1) {
        int u = (t < BWIDTH && t >= off) ? scn[t - off] : 0;
        __syncthreads();
        if (t < BWIDTH) scn[t] += u;
        __syncthreads();
    }
    if (t < BWIDTH) {
        int ex = scn[t] - hist[t];
        scn[t] = ex;
        int node = (b << BSHIFT) + t;
        if (node < N) {
            ptr[node] = base + ex;
            float dd = rsqrtf((float)(hist[t] + 1));   // +1 self-loop
            dis[node] = dd;
            float4 xv = x[node];
            xv.x *= dd; xv.y *= dd; xv.z *= dd; xv.w *= dd;
            zs1[node] = xv;
        }
    }
    __syncthreads();
    for (int i = t; i < cnt; i += 256) {
        unsigned p = useC ? ecache[i] : staging[base + i];
        int c = p >> 17;
        int pos = base + scn[c] + atomicAdd(&fl[c], 1);
        csr[pos] = (int)(p & 0x1FFFFu);
    }
}

// ---------------- GNN compute ----------------

// 4 lanes/node, lane-per-edge-strided gather of zs1 + fused MLP -> fp8 zs2
__global__ __launch_bounds__(256) void k_prop1c(const float4* __restrict__ zs1,
        const int* __restrict__ csr, const int* __restrict__ ptr,
        const float* __restrict__ dis, const float* __restrict__ W1,
        const float* __restrict__ b1, const float* __restrict__ W2,
        unsigned* __restrict__ zs2f8, int n) {
    __shared__ float sW1[256], sb1[64], sW2[2048];
    int t = threadIdx.x;
    sW1[t] = W1[t];
    if (t < 64) sb1[t] = b1[t];
    for (int i = t; i < 2048; i += 256) sW2[i] = W2[i];
    __syncthreads();
    int l = t & 3;
    int v = blockIdx.x * 64 + (t >> 2);
    float ax = 0.f, ay = 0.f, az = 0.f, aw = 0.f;
    int beg = 0, end = 0;
    if (v < n) { beg = ptr[v]; end = ptr[v + 1]; }
    int k = beg + l;
    for (; k + 4 < end; k += 8) {                    // 2 independent chains
        int s0 = csr[k], s1 = csr[k + 4];
        float4 u0 = zs1[s0], u1 = zs1[s1];
        ax += u0.x + u1.x; ay += u0.y + u1.y;
        az += u0.z + u1.z; aw += u0.w + u1.w;
    }
    if (k < end) {
        float4 u = zs1[csr[k]];
        ax += u.x; ay += u.y; az += u.z; aw += u.w;
    }
    ax += __shfl_xor(ax, 1, 4); ax += __shfl_xor(ax, 2, 4);
    ay += __shfl_xor(ay, 1, 4); ay += __shfl_xor(ay, 2, 4);
    az += __shfl_xor(az, 1, 4); az += __shfl_xor(az, 2, 4);
    aw += __shfl_xor(aw, 1, 4); aw += __shfl_xor(aw, 2, 4);
    if (v >= n) return;
    float4 self = zs1[v];
    float d = dis[v];
    float p0 = (ax + self.x) * d, p1 = (ay + self.y) * d;
    float p2 = (az + self.z) * d, p3 = (aw + self.w) * d;
    float acc[8];
#pragma unroll
    for (int m = 0; m < 8; m++) acc[m] = 0.f;
    int col = l * 8;
    for (int kk = 0; kk < 64; kk++) {
        float tv = fmaxf(p0 * sW1[kk] + p1 * sW1[64 + kk] + p2 * sW1[128 + kk]
                         + p3 * sW1[192 + kk] + sb1[kk], 0.f);
        const float* w2 = &sW2[kk * 32 + col];
#pragma unroll
        for (int m = 0; m < 8; m++) acc[m] += tv * w2[m];
    }
    zs2f8[(size_t)v * 8 + 2 * l]     = enc4(acc[0] * d, acc[1] * d, acc[2] * d, acc[3] * d);
    zs2f8[(size_t)v * 8 + 2 * l + 1] = enc4(acc[4] * d, acc[5] * d, acc[6] * d, acc[7] * d);
}

#define DEC_ADD(W, B) { float q_[4]; dec4((W), q_); \
    a[(B) + 0] += q_[0]; a[(B) + 1] += q_[1]; a[(B) + 2] += q_[2]; a[(B) + 3] += q_[3]; }
#define ACC8(WA, WB) { DEC_ADD((WA).x, 0) DEC_ADD((WA).y, 4) DEC_ADD((WA).z, 8) \
    DEC_ADD((WA).w, 12) DEC_ADD((WB).x, 16) DEC_ADD((WB).y, 20) DEC_ADD((WB).z, 24) \
    DEC_ADD((WB).w, 28) }

// 4 lanes/node, lane-per-edge-strided: full 32B fp8 record per lane per edge,
// 4-lane butterfly reduce, lane0 finalizes relu(+b2) + mean-pool partials
__global__ __launch_bounds__(256) void k_prop2c(const uint4* __restrict__ zs4,
        const int* __restrict__ csr, const int* __restrict__ ptr,
        const float* __restrict__ dis, const float* __restrict__ b2,
        float* __restrict__ gsum, int n) {
    __shared__ float gacc[32];
    __shared__ float sb2[32];
    int t = threadIdx.x;
    if (t < 32) { gacc[t] = 0.f; sb2[t] = b2[t]; }
    __syncthreads();
    int l = t & 3;
    int v = blockIdx.x * 64 + (t >> 2);
    float a[32];
#pragma unroll
    for (int m = 0; m < 32; m++) a[m] = 0.f;
    int beg = 0, end = 0;
    if (v < n) { beg = ptr[v]; end = ptr[v + 1]; }
    int k = beg + l;
    for (; k + 4 < end; k += 8) {                    // 2 independent chains
        int s0 = csr[k], s1 = csr[k + 4];
        uint4 wa0 = zs4[(size_t)s0 * 2], wb0 = zs4[(size_t)s0 * 2 + 1];
        uint4 wa1 = zs4[(size_t)s1 * 2], wb1 = zs4[(size_t)s1 * 2 + 1];
        ACC8(wa0, wb0)
        ACC8(wa1, wb1)
    }
    if (k < end) {
        int s = csr[k];
        uint4 wa = zs4[(size_t)s * 2], wb = zs4[(size_t)s * 2 + 1];
        ACC8(wa, wb)
    }
#pragma unroll
    for (int m = 0; m < 32; m++) {
        a[m] += __shfl_xor(a[m], 1, 4);
        a[m] += __shfl_xor(a[m], 2, 4);
    }
    if (l == 0 && v < n) {
        uint4 sa = zs4[(size_t)v * 2], sb = zs4[(size_t)v * 2 + 1];
        ACC8(sa, sb)                                  // self term
        float d = dis[v];
#pragma unroll
        for (int m = 0; m < 32; m++) {
            float r = fmaxf(a[m] * d + sb2[m], 0.f);
            atomicAdd(&gacc[m], r);
        }
    }
    __syncthreads();
    if (t < 32) atomicAdd(&gsum[t], gacc[t]);
}

__global__ void k_final(const float* __restrict__ gsum, const float* __restrict__ Wfc,
                        const float* __restrict__ bfc, float* __restrict__ out, int n) {
    __shared__ float s[32];
    int t = threadIdx.x;
    if (t < 32) s[t] = (gsum[t] / (float)n) * Wfc[t];
    __syncthreads();
    if (t == 0) {
        float a = 0.f;
        for (int i = 0; i < 32; i++) a += s[i];
        a += bfc[0];
        out[0] = 1.f / (1.f + expf(-a));
    }
}

// ---------------- launch ----------------

extern "C" void kernel_launch(void* const* d_in, const int* in_sizes, int n_in,
                              void* d_out, int out_size, void* d_ws, size_t ws_size,
                              hipStream_t stream) {
    const float* x    = (const float*)d_in[0];
    const int*   ei   = (const int*)d_in[1];     // int32 per harness contract
    const float* W1   = (const float*)d_in[2];
    const float* b1   = (const float*)d_in[3];
    const float* W2   = (const float*)d_in[4];
    const float* b2   = (const float*)d_in[5];
    const float* Wfc  = (const float*)d_in[6];
    const float* bfc  = (const float*)d_in[7];
    float* out = (float*)d_out;

    const int N = in_sizes[0] / 4;
    const int E = in_sizes[1] / 2;
    const int E4 = E / 4;
    const int nbuck = (N + BWIDTH - 1) >> BSHIFT;      // 782
    const int total = nbuck * PBLK;                    // 200192
    const int nch   = (total + 1023) / 1024;           // 196 (<=1024)

    auto align = [](size_t v) { return (v + 255) & ~(size_t)255; };
    char* w = (char*)d_ws;
    int*      hh      = (int*)w;      w += align((size_t)total * 4);
    int*      part    = (int*)w;      w += align(1024 * 4);
    // staging (E*4) aliases zs2f8 (N*32B <= E*4): staging dead after k_build
    char* S = w;                      w += align((size_t)E * 4);
    unsigned* staging = (unsigned*)S;
    unsigned* zs2f8   = (unsigned*)S;
    float*    dis     = (float*)w;    w += align((size_t)N * 4);
    float*    zs1     = (float*)w;    w += align((size_t)N * 16);
    int*      ptr     = (int*)w;      w += align(((size_t)N + 1) * 4);
    int*      csr     = (int*)w;      w += align((size_t)E * 4);
    float*    gsum    = (float*)w;    w += align(32 * 4);

    const int nbn = (N + 63) / 64;    // 4 lanes/node, 64 nodes per 256-block

    k_histb<<<PBLK, PTHR, 0, stream>>>((const v4i*)(ei + E), E4, nbuck, hh);
    k_scanA<<<nch, 1024, 0, stream>>>(hh, total, part);
    k_scanB<<<1, 1024, 0, stream>>>(part, nch, gsum, ptr, N, E);
    k_scanC<<<nch, 1024, 0, stream>>>(hh, total, part);
    k_place<<<PBLK, PTHR, 0, stream>>>((const v4i*)ei, (const v4i*)(ei + E),
                                       hh, staging, E4, nbuck);
    k_build<<<nbuck, 256, 0, stream>>>(staging, hh, ptr, dis, csr,
                                       (const float4*)x, (float4*)zs1, N, E, nbuck);
    k_prop1c<<<nbn, 256, 0, stream>>>((const float4*)zs1, csr, ptr, dis,
                                      W1, b1, W2, zs2f8, N);
    k_prop2c<<<nbn, 256, 0, stream>>>((const uint4*)zs2f8, csr, ptr, dis, b2, gsum, N);
    k_final<<<1, 64, 0, stream>>>(gsum, Wfc, bfc, out, N);
}

// Round 10
// 184.844 us; speedup vs baseline: 4.6955x; 1.0243x over previous
//
#include <hip/hip_runtime.h>

#define BSHIFT 7
#define BWIDTH 128
#define PBLK   256        // chunks for hist/place (also their grid size)
#define PTHR   1024
#define ECAP   6144       // LDS edge cache in k_build (24KB); avg bucket ~4100
#define SENT   0x7fffffff

typedef int v4i __attribute__((ext_vector_type(4)));
typedef float v2f __attribute__((ext_vector_type(2)));

// ---------------- fp8 e4m3 helpers (HW cvt with manual fallback) ----------------

#if __has_builtin(__builtin_amdgcn_cvt_pk_f32_fp8) && __has_builtin(__builtin_amdgcn_cvt_pk_fp8_f32)
#define FP8_HW 1
#else
#define FP8_HW 0
#endif

__device__ __forceinline__ unsigned enc1_sw(float f) {
    unsigned u = __float_as_uint(f), s = u >> 31;
    float m = fabsf(f);
    unsigned code;
    if (!(m == m)) code = 0x7F;
    else if (m >= 448.f) code = 0x7E;
    else if (m < 0.015625f) {
        code = (unsigned)(int)rintf(m * 512.f);
    } else {
        int e = (int)((__float_as_uint(m) >> 23) & 255) - 127;
        if (e > 8) e = 8;
        float sc = __uint_as_float((unsigned)(130 - e) << 23);
        int qi = (int)rintf(m * sc);
        if (qi >= 16) { e++; qi = 8; }
        code = (e > 8) ? 0x7E : (((unsigned)(e + 7) << 3) | (unsigned)(qi - 8));
    }
    return code | (s << 7);
}

__device__ __forceinline__ float dec1_sw(unsigned b) {
    unsigned s = b >> 7, e = (b >> 3) & 15, m = b & 7;
    float v;
    if (e == 0) v = (float)m * 0.001953125f;
    else        v = (float)(8 + m) * __uint_as_float((e + 117) << 23);
    return s ? -v : v;
}

__device__ __forceinline__ unsigned enc4(float f0, float f1, float f2, float f3) {
#if FP8_HW
    int w = __builtin_amdgcn_cvt_pk_fp8_f32(f0, f1, 0, false);
    w = __builtin_amdgcn_cvt_pk_fp8_f32(f2, f3, w, true);
    return (unsigned)w;
#else
    return enc1_sw(f0) | (enc1_sw(f1) << 8) | (enc1_sw(f2) << 16) | (enc1_sw(f3) << 24);
#endif
}

__device__ __forceinline__ void dec4(unsigned w, float* o) {
#if FP8_HW
    v2f lo = __builtin_amdgcn_cvt_pk_f32_fp8((int)w, false);
    v2f hi = __builtin_amdgcn_cvt_pk_f32_fp8((int)w, true);
    o[0] = lo[0]; o[1] = lo[1]; o[2] = hi[0]; o[3] = hi[1];
#else
    o[0] = dec1_sw(w & 255); o[1] = dec1_sw((w >> 8) & 255);
    o[2] = dec1_sw((w >> 16) & 255); o[3] = dec1_sw(w >> 24);
#endif
}

// ---------------- bucket-grouped edge staging (global-atomic-free) ----------------

__global__ __launch_bounds__(PTHR) void k_histb(const v4i* __restrict__ col4,
        int E4, int nbuck, int* __restrict__ hh) {
    __shared__ int h[1024];
    int t = threadIdx.x;
    for (int i = t; i < nbuck; i += PTHR) h[i] = 0;
    __syncthreads();
    int per = (E4 + PBLK - 1) / PBLK;
    int beg = blockIdx.x * per;
    int end = min(beg + per, E4);
    for (int i = beg + t; i < end; i += PTHR) {
        v4i c = __builtin_nontemporal_load(&col4[i]);
        atomicAdd(&h[c[0] >> BSHIFT], 1);
        atomicAdd(&h[c[1] >> BSHIFT], 1);
        atomicAdd(&h[c[2] >> BSHIFT], 1);
        atomicAdd(&h[c[3] >> BSHIFT], 1);
    }
    __syncthreads();
    for (int b = t; b < nbuck; b += PTHR)
        hh[b * PBLK + blockIdx.x] = h[b];
}

__global__ __launch_bounds__(1024) void k_scanA(int* __restrict__ hh, int total,
                                                int* __restrict__ part) {
    __shared__ int s[1024];
    int t = threadIdx.x;
    int i = blockIdx.x * 1024 + t;
    int v = (i < total) ? hh[i] : 0;
    s[t] = v;
    __syncthreads();
    for (int off = 1; off < 1024; off <<= 1) {
        int u = (t >= off) ? s[t - off] : 0;
        __syncthreads();
        s[t] += u;
        __syncthreads();
    }
    if (i < total) hh[i] = s[t] - v;
    if (t == 1023) part[blockIdx.x] = s[t];
}

__global__ __launch_bounds__(1024) void k_scanB(int* __restrict__ part, int nch,
        float* __restrict__ gsum, int* __restrict__ ptr, int N, int E) {
    __shared__ int s[1024];
    int t = threadIdx.x;
    int v = (t < nch) ? part[t] : 0;
    s[t] = v;
    __syncthreads();
    for (int off = 1; off < 1024; off <<= 1) {
        int u = (t >= off) ? s[t - off] : 0;
        __syncthreads();
        s[t] += u;
        __syncthreads();
    }
    if (t < nch) part[t] = s[t] - v;
    if (t < 32) gsum[t] = 0.f;
    if (t == 0) ptr[N] = E;
}

__global__ __launch_bounds__(1024) void k_scanC(int* __restrict__ hh, int total,
                                                const int* __restrict__ part) {
    int i = blockIdx.x * 1024 + threadIdx.x;
    if (i < total) hh[i] += part[blockIdx.x];
}

__global__ __launch_bounds__(PTHR) void k_place(const v4i* __restrict__ row4,
        const v4i* __restrict__ col4, const int* __restrict__ hh,
        unsigned* __restrict__ staging, int E4, int nbuck) {
    __shared__ int sbase[1024];
    __shared__ int lfill[1024];
    int t = threadIdx.x;
    for (int b = t; b < nbuck; b += PTHR) {
        sbase[b] = hh[b * PBLK + blockIdx.x];
        lfill[b] = 0;
    }
    __syncthreads();
    int per = (E4 + PBLK - 1) / PBLK;
    int beg = blockIdx.x * per;
    int end = min(beg + per, E4);
    for (int i = beg + t; i < end; i += PTHR) {
        v4i c = __builtin_nontemporal_load(&col4[i]);
        v4i r = __builtin_nontemporal_load(&row4[i]);
#pragma unroll
        for (int q = 0; q < 4; q++) {
            int b = c[q] >> BSHIFT;
            int pos = sbase[b] + atomicAdd(&lfill[b], 1);
            staging[pos] = (unsigned)r[q] | ((unsigned)(c[q] & (BWIDTH - 1)) << 17);
        }
    }
}

// per-bucket: degrees -> ptr/dis/zs1, degree-sorted perm, CSR slices
__global__ __launch_bounds__(256) void k_build(const unsigned* __restrict__ staging,
        const int* __restrict__ hh, int* __restrict__ ptr, float* __restrict__ dis,
        int* __restrict__ csr, const float4* __restrict__ x, float4* __restrict__ zs1,
        int* __restrict__ perm, int N, int E, int nbuck) {
    __shared__ unsigned ecache[ECAP];
    __shared__ int hist[BWIDTH], scn[BWIDTH], fl[BWIDTH];
    int b = blockIdx.x;
    int base = hh[b * PBLK];
    int nxt  = (b + 1 < nbuck) ? hh[(b + 1) * PBLK] : E;
    int cnt = nxt - base;
    int t = threadIdx.x;
    bool useC = (cnt <= ECAP);
    if (t < BWIDTH) { hist[t] = 0; fl[t] = 0; }
    __syncthreads();
    if (useC) {
        for (int i = t; i < cnt; i += 256) {
            unsigned p = staging[base + i];
            ecache[i] = p;
            atomicAdd(&hist[p >> 17], 1);
        }
    } else {
        for (int i = t; i < cnt; i += 256)
            atomicAdd(&hist[staging[base + i] >> 17], 1);
    }
    __syncthreads();
    if (t < BWIDTH) scn[t] = hist[t];
    __syncthreads();
    for (int off = 1; off < BWIDTH; off <<= 1) {
        int u = (t < BWIDTH && t >= off) ? scn[t - off] : 0;
        __syncthreads();
        if (t < BWIDTH) scn[t] += u;
        __syncthreads();
    }
    if (t < BWIDTH) {
        int ex = scn[t] - hist[t];
        scn[t] = ex;
        int node = (b << BSHIFT) + t;
        // degree-rank sort within bucket (descending degree)
        int mydeg = (node < N) ? hist[t] : -1;
        int rank = 0;
        for (int j = 0; j < BWIDTH; j++) {
            int nj = (b << BSHIFT) + j;
            int dj = (nj < N) ? hist[j] : -1;
            rank += (dj > mydeg) || (dj == mydeg && j < t);
        }
        perm[(b << BSHIFT) + rank] = (node < N) ? node : SENT;
        if (node < N) {
            ptr[node] = base + ex;
            float dd = rsqrtf((float)(hist[t] + 1));   // +1 self-loop
            dis[node] = dd;
            float4 xv = x[node];
            xv.x *= dd; xv.y *= dd; xv.z *= dd; xv.w *= dd;
            zs1[node] = xv;
        }
    }
    __syncthreads();
    for (int i = t; i < cnt; i += 256) {
        unsigned p = useC ? ecache[i] : staging[base + i];
        int c = p >> 17;
        int pos = base + scn[c] + atomicAdd(&fl[c], 1);
        csr[pos] = (int)(p & 0x1FFFFu);
    }
}

// ---------------- GNN compute ----------------

// 4 lanes/node (perm order), 4-chain gather of zs1 + fused MLP -> fp8 zs2
__global__ __launch_bounds__(256) void k_prop1c(const float4* __restrict__ zs1,
        const int* __restrict__ csr, const int* __restrict__ ptr,
        const float* __restrict__ dis, const int* __restrict__ perm,
        const float* __restrict__ W1, const float* __restrict__ b1,
        const float* __restrict__ W2, unsigned* __restrict__ zs2f8, int n, int NP) {
    __shared__ float sW1[256], sb1[64], sW2[2048];
    int t = threadIdx.x;
    sW1[t] = W1[t];
    if (t < 64) sb1[t] = b1[t];
    for (int i = t; i < 2048; i += 256) sW2[i] = W2[i];
    __syncthreads();
    int l = t & 3;
    int gid = blockIdx.x * 64 + (t >> 2);
    int v = (gid < NP) ? perm[gid] : SENT;
    float ax = 0.f, ay = 0.f, az = 0.f, aw = 0.f;
    int beg = 0, end = 0;
    if (v < n) { beg = ptr[v]; end = ptr[v + 1]; }
    int k = beg + l;
    for (; k + 12 < end; k += 16) {                  // 4 independent chains
        int s0 = csr[k], s1 = csr[k + 4], s2 = csr[k + 8], s3 = csr[k + 12];
        float4 u0 = zs1[s0], u1 = zs1[s1], u2 = zs1[s2], u3 = zs1[s3];
        ax += (u0.x + u1.x) + (u2.x + u3.x);
        ay += (u0.y + u1.y) + (u2.y + u3.y);
        az += (u0.z + u1.z) + (u2.z + u3.z);
        aw += (u0.w + u1.w) + (u2.w + u3.w);
    }
    for (; k < end; k += 4) {
        float4 u = zs1[csr[k]];
        ax += u.x; ay += u.y; az += u.z; aw += u.w;
    }
    ax += __shfl_xor(ax, 1, 4); ax += __shfl_xor(ax, 2, 4);
    ay += __shfl_xor(ay, 1, 4); ay += __shfl_xor(ay, 2, 4);
    az += __shfl_xor(az, 1, 4); az += __shfl_xor(az, 2, 4);
    aw += __shfl_xor(aw, 1, 4); aw += __shfl_xor(aw, 2, 4);
    if (v >= n) return;
    float4 self = zs1[v];
    float d = dis[v];
    float p0 = (ax + self.x) * d, p1 = (ay + self.y) * d;
    float p2 = (az + self.z) * d, p3 = (aw + self.w) * d;
    float acc[8];
#pragma unroll
    for (int m = 0; m < 8; m++) acc[m] = 0.f;
    int col = l * 8;
    for (int kk = 0; kk < 64; kk++) {
        float tv = fmaxf(p0 * sW1[kk] + p1 * sW1[64 + kk] + p2 * sW1[128 + kk]
                         + p3 * sW1[192 + kk] + sb1[kk], 0.f);
        const float* w2 = &sW2[kk * 32 + col];
#pragma unroll
        for (int m = 0; m < 8; m++) acc[m] += tv * w2[m];
    }
    zs2f8[(size_t)v * 8 + 2 * l]     = enc4(acc[0] * d, acc[1] * d, acc[2] * d, acc[3] * d);
    zs2f8[(size_t)v * 8 + 2 * l + 1] = enc4(acc[4] * d, acc[5] * d, acc[6] * d, acc[7] * d);
}

// 8 lanes/node (perm order), feature-split, 8-deep edge unroll:
// lanes j=0..7 of a group load zs2f8[s*8+j] (32B coalesced per edge)
__global__ __launch_bounds__(256) void k_prop2d(const unsigned* __restrict__ zs,
        const int* __restrict__ csr, const int* __restrict__ ptr,
        const float* __restrict__ dis, const int* __restrict__ perm,
        const float* __restrict__ b2, float* __restrict__ gsum, int n, int NP) {
    __shared__ float gacc[32];
    __shared__ float sb2[32];
    int t = threadIdx.x;
    if (t < 32) { gacc[t] = 0.f; sb2[t] = b2[t]; }
    __syncthreads();
    int j = t & 7;
    int gid = blockIdx.x * 32 + (t >> 3);
    int v = (gid < NP) ? perm[gid] : SENT;
    float a0 = 0.f, a1 = 0.f, a2 = 0.f, a3 = 0.f;
    int beg = 0, end = 0;
    if (v < n) { beg = ptr[v]; end = ptr[v + 1]; }
    int k = beg;
    for (; k + 7 < end; k += 8) {                    // 8 edges in flight
        int s0 = csr[k],     s1 = csr[k + 1], s2 = csr[k + 2], s3 = csr[k + 3];
        int s4 = csr[k + 4], s5 = csr[k + 5], s6 = csr[k + 6], s7 = csr[k + 7];
        unsigned w0 = zs[(size_t)s0 * 8 + j], w1 = zs[(size_t)s1 * 8 + j];
        unsigned w2 = zs[(size_t)s2 * 8 + j], w3 = zs[(size_t)s3 * 8 + j];
        unsigned w4 = zs[(size_t)s4 * 8 + j], w5 = zs[(size_t)s5 * 8 + j];
        unsigned w6 = zs[(size_t)s6 * 8 + j], w7 = zs[(size_t)s7 * 8 + j];
        float q0[4], q1[4], q2[4], q3[4], q4[4], q5[4], q6[4], q7[4];
        dec4(w0, q0); dec4(w1, q1); dec4(w2, q2); dec4(w3, q3);
        dec4(w4, q4); dec4(w5, q5); dec4(w6, q6); dec4(w7, q7);
        a0 += ((q0[0] + q1[0]) + (q2[0] + q3[0])) + ((q4[0] + q5[0]) + (q6[0] + q7[0]));
        a1 += ((q0[1] + q1[1]) + (q2[1] + q3[1])) + ((q4[1] + q5[1]) + (q6[1] + q7[1]));
        a2 += ((q0[2] + q1[2]) + (q2[2] + q3[2])) + ((q4[2] + q5[2]) + (q6[2] + q7[2]));
        a3 += ((q0[3] + q1[3]) + (q2[3] + q3[3])) + ((q4[3] + q5[3]) + (q6[3] + q7[3]));
    }
    for (; k < end; k++) {
        unsigned w = zs[(size_t)csr[k] * 8 + j];
        float q[4];
        dec4(w, q);
        a0 += q[0]; a1 += q[1]; a2 += q[2]; a3 += q[3];
    }
    if (v < n) {
        float q[4];
        dec4(zs[(size_t)v * 8 + j], q);              // self term
        a0 += q[0]; a1 += q[1]; a2 += q[2]; a3 += q[3];
        float d = dis[v];
        int f = j * 4;
        atomicAdd(&gacc[f + 0], fmaxf(a0 * d + sb2[f + 0], 0.f));
        atomicAdd(&gacc[f + 1], fmaxf(a1 * d + sb2[f + 1], 0.f));
        atomicAdd(&gacc[f + 2], fmaxf(a2 * d + sb2[f + 2], 0.f));
        atomicAdd(&gacc[f + 3], fmaxf(a3 * d + sb2[f + 3], 0.f));
    }
    __syncthreads();
    if (t < 32) atomicAdd(&gsum[t], gacc[t]);
}

__global__ void k_final(const float* __restrict__ gsum, const float* __restrict__ Wfc,
                        const float* __restrict__ bfc, float* __restrict__ out, int n) {
    __shared__ float s[32];
    int t = threadIdx.x;
    if (t < 32) s[t] = (gsum[t] / (float)n) * Wfc[t];
    __syncthreads();
    if (t == 0) {
        float a = 0.f;
        for (int i = 0; i < 32; i++) a += s[i];
        a += bfc[0];
        out[0] = 1.f / (1.f + expf(-a));
    }
}

// ---------------- launch ----------------

extern "C" void kernel_launch(void* const* d_in, const int* in_sizes, int n_in,
                              void* d_out, int out_size, void* d_ws, size_t ws_size,
                              hipStream_t stream) {
    const float* x    = (const float*)d_in[0];
    const int*   ei   = (const int*)d_in[1];     // int32 per harness contract
    const float* W1   = (const float*)d_in[2];
    const float* b1   = (const float*)d_in[3];
    const float* W2   = (const float*)d_in[4];
    const float* b2   = (const float*)d_in[5];
    const float* Wfc  = (const float*)d_in[6];
    const float* bfc  = (const float*)d_in[7];
    float* out = (float*)d_out;

    const int N = in_sizes[0] / 4;
    const int E = in_sizes[1] / 2;
    const int E4 = E / 4;
    const int nbuck = (N + BWIDTH - 1) >> BSHIFT;      // 782
    const int NP    = nbuck << BSHIFT;                 // 100096 perm slots
    const int total = nbuck * PBLK;                    // 200192
    const int nch   = (total + 1023) / 1024;           // 196 (<=1024)

    auto align = [](size_t v) { return (v + 255) & ~(size_t)255; };
    char* w = (char*)d_ws;
    int*      hh      = (int*)w;      w += align((size_t)total * 4);
    int*      part    = (int*)w;      w += align(1024 * 4);
    // staging (E*4) aliases zs2f8 (N*32B <= E*4): staging dead after k_build
    char* S = w;                      w += align((size_t)E * 4);
    unsigned* staging = (unsigned*)S;
    unsigned* zs2f8   = (unsigned*)S;
    float*    dis     = (float*)w;    w += align((size_t)N * 4);
    float*    zs1     = (float*)w;    w += align((size_t)N * 16);
    int*      ptr     = (int*)w;      w += align(((size_t)N + 1) * 4);
    int*      csr     = (int*)w;      w += align((size_t)E * 4);
    int*      perm    = (int*)w;      w += align((size_t)NP * 4);
    float*    gsum    = (float*)w;    w += align(32 * 4);

    k_histb<<<PBLK, PTHR, 0, stream>>>((const v4i*)(ei + E), E4, nbuck, hh);
    k_scanA<<<nch, 1024, 0, stream>>>(hh, total, part);
    k_scanB<<<1, 1024, 0, stream>>>(part, nch, gsum, ptr, N, E);
    k_scanC<<<nch, 1024, 0, stream>>>(hh, total, part);
    k_place<<<PBLK, PTHR, 0, stream>>>((const v4i*)ei, (const v4i*)(ei + E),
                                       hh, staging, E4, nbuck);
    k_build<<<nbuck, 256, 0, stream>>>(staging, hh, ptr, dis, csr,
                                       (const float4*)x, (float4*)zs1, perm, N, E, nbuck);
    k_prop1c<<<(NP + 63) / 64, 256, 0, stream>>>((const float4*)zs1, csr, ptr, dis, perm,
                                                 W1, b1, W2, zs2f8, N, NP);
    k_prop2d<<<(NP + 31) / 32, 256, 0, stream>>>(zs2f8, csr, ptr, dis, perm,
                                                 b2, gsum, N, NP);
    k_final<<<1, 64, 0, stream>>>(gsum, Wfc, bfc, out, N);
}